// Round 6
// baseline (180.104 us; speedup 1.0000x reference)
//
#include <hip/hip_runtime.h>
#include <hip/hip_bf16.h>
#include <math.h>

#define B_    128
#define LQ_   64
#define LD_   512
#define E_    300
#define K_    11
#define NCH   8      // d-chunks of 64 rows
#define DCH   64
#define QROWS 32     // q rows per block (2 q-halves)
#define ROWS  96     // 32 Q + 64 D staged rows
#define STR   328    // bf16 elems per staged row (320 data-padded + 8)
#define NT    10     // K-steps of 32 (E padded 300->320)
#define NSUB  32     // psum d-subchunks of 16 rows

typedef __bf16  bf16x8  __attribute__((ext_vector_type(8)));
typedef float   floatx4 __attribute__((ext_vector_type(4)));

__device__ __constant__ float MU_C[K_] =
    {1.0f, 0.9f, 0.7f, 0.5f, 0.3f, 0.1f, -0.1f, -0.3f, -0.5f, -0.7f, -0.9f};
__device__ __constant__ float NEGC_C[K_] =
    {-500000.0f, -50.0f, -50.0f, -50.0f, -50.0f, -50.0f,
     -50.0f, -50.0f, -50.0f, -50.0f, -50.0f};

__device__ __forceinline__ unsigned int pk2(float x, float y) {
    __hip_bfloat162 h = __float22bfloat162_rn(make_float2(x, y));
    union { __hip_bfloat162 h2; unsigned int u; } c;
    c.h2 = h;
    return c.u;
}

__device__ __forceinline__ float bsq(unsigned int u) {
    float lo = __uint_as_float(u << 16);
    float hi = __uint_as_float(u & 0xffff0000u);
    return fmaf(lo, lo, hi * hi);
}

// Block = (batch, d-chunk of 64, q-half of 32), 512 thr = 8 waves.
// Phase 1: burst-stage ALL 96 fp32 rows -> bf16 LDS (every thread fires its
//          ~8 independent 32-B loads back-to-back; nothing consumes them until
//          the barrier) -> maximum outstanding-load depth.
// Phase 2: row norms from staged bf16 (no extra global traffic).
// Phase 3: load-free MFMA K-loop; wave w = (qt=w&1, dt=w>>1) does one 16x16.
// Phase 4: RBF pooling epilogue -> psum[B][32][64][K].
__global__ __launch_bounds__(512, 4) void knrm_main(
    const float* __restrict__ Q, const float* __restrict__ D,
    const float* __restrict__ mask_d, float* __restrict__ psum)
{
    const int b   = blockIdx.y;
    const int ch  = blockIdx.x >> 1;
    const int qh  = blockIdx.x & 1;
    const int q0  = qh * QROWS, d0 = ch * DCH;
    const int tid = threadIdx.x;
    const int lane = tid & 63, w = tid >> 6;
    const int quad = lane >> 4, l15 = lane & 15;
    const int qt = w & 1, dt = w >> 1;

    __shared__ __align__(16) unsigned short sh[ROWS * STR];  // rows 0-31 Q, 32-95 D
    __shared__ float qinv_s[QROWS];
    __shared__ float dinv_s[DCH];
    __shared__ float md_s[DCH];

    const float* qbase = Q + ((size_t)b * LQ_ + q0) * E_;
    const float* dbase = D + ((size_t)b * LD_ + d0) * E_;

    // ---- Phase 1: burst staging. 3840 units of 8 floats -> 8 bf16 ----
#pragma unroll
    for (int kk = 0; kk < 8; ++kk) {
        int g = tid + kk * 512;
        if (g < 3840) {
            int row = (unsigned)g / 40u;
            int u   = g - row * 40;
            int e   = u * 8;
            const float* src = (row < QROWS)
                ? (qbase + (size_t)row * E_)
                : (dbase + (size_t)(row - QROWS) * E_);
            float4 v0 = (e     < E_) ? *(const float4*)(src + e)
                                     : make_float4(0.f, 0.f, 0.f, 0.f);
            float4 v1 = (e + 4 < E_) ? *(const float4*)(src + e + 4)
                                     : make_float4(0.f, 0.f, 0.f, 0.f);
            *(uint4*)&sh[row * STR + e] =
                make_uint4(pk2(v0.x, v0.y), pk2(v0.z, v0.w),
                           pk2(v1.x, v1.y), pk2(v1.z, v1.w));
        }
    }
    if (tid < DCH) md_s[tid] = mask_d[(size_t)b * LD_ + d0 + tid];
    __syncthreads();

    // ---- Phase 2: row norms from staged bf16 (4 threads/row x 80 elems) ----
    if (tid < 4 * ROWS) {
        int row = tid >> 2, part = tid & 3;
        float ss = 0.f;
#pragma unroll
        for (int j = 0; j < 10; ++j) {
            uint4 uv = *(const uint4*)&sh[row * STR + part * 80 + j * 8];
            ss += bsq(uv.x) + bsq(uv.y) + bsq(uv.z) + bsq(uv.w);
        }
        ss += __shfl_xor(ss, 1);
        ss += __shfl_xor(ss, 2);
        if (part == 0) {
            float inv = 1.0f / fmaxf(sqrtf(ss), 1e-12f);
            if (row < QROWS) qinv_s[row] = inv;
            else             dinv_s[row - QROWS] = inv;
        }
    }

    // ---- Phase 3: load-free MFMA K-loop ----
    floatx4 acc = {0.f, 0.f, 0.f, 0.f};
    const int arow = (qt * 16 + l15) * STR;
    const int brow = (QROWS + dt * 16 + l15) * STR;
#pragma unroll
    for (int t = 0; t < NT; ++t) {
        bf16x8 af = *(const bf16x8*)&sh[arow + t * 32 + quad * 8];
        bf16x8 bf = *(const bf16x8*)&sh[brow + t * 32 + quad * 8];
        acc = __builtin_amdgcn_mfma_f32_16x16x32_bf16(af, bf, acc, 0, 0, 0);
    }
    __syncthreads();  // norm writes visible to all waves

    // ---- Phase 4: RBF pooling. Lane owns 1 d-col (l15) x 4 q-rows ----
    const float dinv = dinv_s[dt * 16 + l15];
    const float md   = md_s[dt * 16 + l15];

    float kacc[4][K_];
#pragma unroll
    for (int r = 0; r < 4; ++r) {
        float s = acc[r] * qinv_s[qt * 16 + quad * 4 + r] * dinv;
#pragma unroll
        for (int k = 0; k < K_; ++k) {
            float df = s - MU_C[k];
            kacc[r][k] = __expf(df * df * NEGC_C[k]) * md;
        }
    }
#pragma unroll
    for (int m = 1; m <= 8; m <<= 1)
#pragma unroll
        for (int r = 0; r < 4; ++r)
#pragma unroll
            for (int k = 0; k < K_; ++k)
                kacc[r][k] += __shfl_xor(kacc[r][k], m);

    if (l15 == 0) {
        const int dsub = ch * 4 + dt;
#pragma unroll
        for (int r = 0; r < 4; ++r) {
            int q = q0 + qt * 16 + quad * 4 + r;
            const size_t base = (((size_t)b * NSUB + dsub) * LQ_ + q) * K_;
#pragma unroll
            for (int k = 0; k < K_; ++k) psum[base + k] = kacc[r][k];
        }
    }
}

// Combine 32 sub-chunk partials, log-pool, dense + tanh. 704 thr = (q,k) pairs.
__global__ __launch_bounds__(704) void knrm_final(
    const float* __restrict__ psum, const float* __restrict__ mask_q,
    const float* __restrict__ dw, const float* __restrict__ db,
    float* __restrict__ out)
{
    const int b = blockIdx.x;
    const int t = threadIdx.x;          // 0..703
    const int q = (unsigned)t / 11u;
    const int k = t - q * 11;

    float p = 0.f;
#pragma unroll
    for (int c = 0; c < NSUB; ++c)
        p += psum[(((size_t)b * NSUB + c) * LQ_ + q) * K_ + k];
    float v = logf(fmaxf(p, 1e-10f)) * dw[k] * 0.01f * mask_q[(size_t)b * LQ_ + q];

#pragma unroll
    for (int m = 1; m <= 32; m <<= 1) v += __shfl_xor(v, m);

    __shared__ float red[11];
    if ((t & 63) == 0) red[t >> 6] = v;
    __syncthreads();
    if (t == 0) {
        float s = db[0];
#pragma unroll
        for (int i = 0; i < 11; ++i) s += red[i];
        out[b] = tanhf(s);
    }
}

extern "C" void kernel_launch(void* const* d_in, const int* in_sizes, int n_in,
                              void* d_out, int out_size, void* d_ws, size_t ws_size,
                              hipStream_t stream) {
    const float* Q   = (const float*)d_in[0];  // [B, LQ, E]
    const float* D   = (const float*)d_in[1];  // [B, LD, E]
    const float* mq  = (const float*)d_in[2];  // [B, LQ]
    const float* md  = (const float*)d_in[3];  // [B, LD]
    const float* dw  = (const float*)d_in[4];  // [1, K]
    const float* db  = (const float*)d_in[5];  // [1]
    float* out  = (float*)d_out;               // [B, 1]
    float* psum = (float*)d_ws;                // [B][32][LQ][K] = 11.5 MB

    dim3 grid(NCH * 2, B_);                    // (d-chunk x q-half, batch)
    knrm_main<<<grid, 512, 0, stream>>>(Q, D, md, psum);
    knrm_final<<<B_, 704, 0, stream>>>(psum, mq, dw, db, out);
}

// Round 7
// 151.321 us; speedup vs baseline: 1.1902x; 1.1902x over previous
//
#include <hip/hip_runtime.h>
#include <hip/hip_bf16.h>
#include <math.h>

#define B_   128
#define LQ_  64
#define LD_  512
#define E_   300
#define K_   11
#define NCH  8      // d-chunks of 64 rows
#define DCH  64
#define NT   10     // e-tiles of 32 (300 padded to 320)
#define QSTR 328    // Q bf16 LDS row stride (2-way bank alias = free)
#define CSTR 68     // epilogue sims row stride (floats)

typedef __bf16  bf16x8  __attribute__((ext_vector_type(8)));
typedef float   floatx4 __attribute__((ext_vector_type(4)));

__device__ __constant__ float MU_C[K_] =
    {1.0f, 0.9f, 0.7f, 0.5f, 0.3f, 0.1f, -0.1f, -0.3f, -0.5f, -0.7f, -0.9f};
__device__ __constant__ float NEGC_C[K_] =
    {-500000.0f, -50.0f, -50.0f, -50.0f, -50.0f, -50.0f,
     -50.0f, -50.0f, -50.0f, -50.0f, -50.0f};

__device__ __forceinline__ unsigned int pk2(float x, float y) {
    __hip_bfloat162 h = __float22bfloat162_rn(make_float2(x, y));
    union { __hip_bfloat162 h2; unsigned int u; } c;
    c.h2 = h;
    return c.u;
}
__device__ __forceinline__ float bsq(unsigned int u) {
    float lo = __uint_as_float(u << 16);
    float hi = __uint_as_float(u & 0xffff0000u);
    return fmaf(lo, lo, hi * hi);
}

// async global->LDS DMA, 16 B per lane; LDS dst is wave-uniform base + lane*16
__device__ __forceinline__ void async16(const void* g, void* l) {
    __builtin_amdgcn_global_load_lds(
        (const __attribute__((address_space(1))) void*)g,
        (__attribute__((address_space(3))) void*)l, 16, 0, 0);
}
__device__ __forceinline__ void wait_vm(int n) {   // n folds to a constant under unroll
    if (n >= 4)      asm volatile("s_waitcnt vmcnt(4)" ::: "memory");
    else if (n == 2) asm volatile("s_waitcnt vmcnt(2)" ::: "memory");
    else             asm volatile("s_waitcnt vmcnt(0)" ::: "memory");
}

union __align__(16) ShQ {
    unsigned short qs[LQ_ * QSTR];  // 41984 B: K-loop Q (bf16, zero-padded to 320)
    float          cs[LQ_ * CSTR];  // 17408 B: epilogue normalized sims
};

// Block = (batch, d-chunk of 64), 256 thr = 4 waves.
// Q: staged once -> bf16 LDS. D: global_load_lds DMA into wave-private ring
// (wave w DMAs and consumes ONLY rows w*16..+16) -> zero K-loop barriers;
// explicit vmcnt(4/2/0) keeps 6 copies/wave in flight.
__global__ __launch_bounds__(256, 2) void knrm_main(
    const float* __restrict__ Q, const float* __restrict__ D,
    const float* __restrict__ mask_d, float* __restrict__ psum)
{
    const int b = blockIdx.y, ch = blockIdx.x, d0 = ch * DCH;
    const int tid  = threadIdx.x;
    const int lane = tid & 63;
    const int w    = tid >> 6;
    const int quad = lane >> 4;
    const int l15  = lane & 15;

    __shared__ ShQ sh;
    __shared__ __align__(16) float Dbuf[4][DCH * 32];  // 4-slot ring, 8 KB each
    __shared__ float qinv_s[LQ_];
    __shared__ float md_s[DCH];

    // ---- stage Q (fp32 -> bf16, zero-padded e>=300) ----
    const float* qbase = Q + (size_t)b * LQ_ * E_;
#pragma unroll
    for (int kk = 0; kk < 10; ++kk) {
        int g = tid + kk * 256;                    // 2560 units of 8 elems
        int row = (unsigned)g / 40u;
        int u   = g - row * 40;
        int e   = u * 8;
        const float* src = qbase + (size_t)row * E_;
        float4 v0 = (e     < E_) ? *(const float4*)(src + e)
                                 : make_float4(0.f, 0.f, 0.f, 0.f);
        float4 v1 = (e + 4 < E_) ? *(const float4*)(src + e + 4)
                                 : make_float4(0.f, 0.f, 0.f, 0.f);
        *(uint4*)&sh.qs[row * QSTR + e] =
            make_uint4(pk2(v0.x, v0.y), pk2(v0.z, v0.w),
                       pk2(v1.x, v1.y), pk2(v1.z, v1.w));
    }
    if (tid < DCH) md_s[tid] = mask_d[(size_t)b * LD_ + d0 + tid];
    __syncthreads();

    // ---- q norms from staged bf16 (4 thr/row) ----
    {
        int row = tid >> 2, part = tid & 3;
        float ss = 0.f;
#pragma unroll
        for (int j2 = 0; j2 < 10; ++j2) {
            uint4 uv = *(const uint4*)&sh.qs[row * QSTR + part * 80 + j2 * 8];
            ss += bsq(uv.x) + bsq(uv.y) + bsq(uv.z) + bsq(uv.w);
        }
        ss += __shfl_xor(ss, 1);
        ss += __shfl_xor(ss, 2);
        if (part == 0) qinv_s[row] = 1.0f / fmaxf(sqrtf(ss), 1e-12f);
    }

    // ---- D DMA: wave-private rows, 2 copies (1 KB each) per tile ----
    const char* dbase = (const char*)(D + ((size_t)b * LD_ + d0) * E_);
    auto issueD = [&](int t) {
        const int slot = t & 3;
        int eoff = (lane & 7) * 16;
        if (t == NT - 1 && eoff > 32) eoff = 32;   // stay inside the 1200-B row
        const char* g = dbase + (size_t)(w * 16 + (lane >> 3)) * (E_ * 4)
                      + t * 128 + eoff;
        async16(g,               (void*)&Dbuf[slot][(w * 16) * 32]);
        async16(g + 8 * (E_ * 4),(void*)&Dbuf[slot][(w * 16 + 8) * 32]);
    };
    issueD(0); issueD(1); issueD(2);

    floatx4 acc[4];
    floatx4 zero4 = {0.f, 0.f, 0.f, 0.f};
#pragma unroll
    for (int mt = 0; mt < 4; ++mt) acc[mt] = zero4;
    float ssd = 0.f;

#pragma unroll
    for (int t = 0; t < NT; ++t) {
        const int rem = NT - 1 - t;
        wait_vm(rem >= 2 ? 4 : 2 * rem);           // tile t's 2 copies landed

        const float* bp = &Dbuf[t & 3][(w * 16 + l15) * 32 + quad * 8];
        float4 b0 = *(const float4*)bp;
        float4 b1 = *(const float4*)(bp + 4);
        float bv[8] = {b0.x, b0.y, b0.z, b0.w, b1.x, b1.y, b1.z, b1.w};
        if (t == NT - 1) {                          // mask e >= 300 tail
#pragma unroll
            for (int j = 0; j < 8; ++j)
                if (288 + quad * 8 + j >= E_) bv[j] = 0.f;
        }
#pragma unroll
        for (int j = 0; j < 8; ++j) ssd = fmaf(bv[j], bv[j], ssd);

        union { uint4 u; bf16x8 v; } bc;
        bc.u = make_uint4(pk2(bv[0], bv[1]), pk2(bv[2], bv[3]),
                          pk2(bv[4], bv[5]), pk2(bv[6], bv[7]));
        const int ebase = t * 32 + quad * 8;
#pragma unroll
        for (int mt = 0; mt < 4; ++mt) {
            bf16x8 af = *(const bf16x8*)&sh.qs[(mt * 16 + l15) * QSTR + ebase];
            acc[mt] = __builtin_amdgcn_mfma_f32_16x16x32_bf16(af, bc.v, acc[mt], 0, 0, 0);
        }
        if (t + 3 < NT) issueD(t + 3);  // writes slot (t-1)&3: drained last iter
    }

    // d inv-norm: sum the 4 quads' e-slices (lanes share l15)
    ssd += __shfl_xor(ssd, 16);
    ssd += __shfl_xor(ssd, 32);
    const float dinv = 1.0f / fmaxf(sqrtf(ssd), 1e-12f);

    // ---- epilogue: normalized sims -> LDS (aliases Qs), repartition, pool ----
    __syncthreads();   // all Qs reads done; qinv visible
#pragma unroll
    for (int mt = 0; mt < 4; ++mt) {
#pragma unroll
        for (int r = 0; r < 4; ++r) {
            int q = mt * 16 + quad * 4 + r;
            sh.cs[q * CSTR + w * 16 + l15] = acc[mt][r] * qinv_s[q] * dinv;
        }
    }
    __syncthreads();

    const int pq = tid >> 2, pd = tid & 3;   // q-row x 16-d slice
    float kacc[K_];
#pragma unroll
    for (int k = 0; k < K_; ++k) kacc[k] = 0.f;
#pragma unroll
    for (int j = 0; j < 16; ++j) {
        float s = sh.cs[pq * CSTR + pd * 16 + j];
        float m = md_s[pd * 16 + j];
#pragma unroll
        for (int k = 0; k < K_; ++k) {
            float df = s - MU_C[k];
            kacc[k] = fmaf(__expf(df * df * NEGC_C[k]), m, kacc[k]);
        }
    }
#pragma unroll
    for (int msk = 1; msk <= 2; msk <<= 1)
#pragma unroll
        for (int k = 0; k < K_; ++k) kacc[k] += __shfl_xor(kacc[k], msk);

    if (pd == 0) {
        const size_t base = (((size_t)b * NCH + ch) * LQ_ + pq) * K_;
#pragma unroll
        for (int k = 0; k < K_; ++k) psum[base + k] = kacc[k];
    }
}

// Combine chunk partials, log-pool, dense + tanh. One wave per batch.
__global__ __launch_bounds__(64) void knrm_final(
    const float* __restrict__ psum, const float* __restrict__ mask_q,
    const float* __restrict__ dw, const float* __restrict__ db,
    float* __restrict__ out)
{
    const int b = blockIdx.x;
    const int q = threadIdx.x;  // 0..63

    float t = 0.0f;
#pragma unroll
    for (int k = 0; k < K_; ++k) {
        float p = 0.0f;
#pragma unroll
        for (int c = 0; c < NCH; ++c)
            p += psum[(((size_t)b * NCH + c) * LQ_ + q) * K_ + k];
        p = fmaxf(p, 1e-10f);
        t += logf(p) * dw[k];
    }
    t *= 0.01f * mask_q[(size_t)b * LQ_ + q];

#pragma unroll
    for (int m = 32; m >= 1; m >>= 1) t += __shfl_xor(t, m);
    if (q == 0) out[b] = tanhf(t + db[0]);
}

extern "C" void kernel_launch(void* const* d_in, const int* in_sizes, int n_in,
                              void* d_out, int out_size, void* d_ws, size_t ws_size,
                              hipStream_t stream) {
    const float* Q   = (const float*)d_in[0];  // [B, LQ, E]
    const float* D   = (const float*)d_in[1];  // [B, LD, E]
    const float* mq  = (const float*)d_in[2];  // [B, LQ]
    const float* md  = (const float*)d_in[3];  // [B, LD]
    const float* dw  = (const float*)d_in[4];  // [1, K]
    const float* db  = (const float*)d_in[5];  // [1]
    float* out  = (float*)d_out;               // [B, 1]
    float* psum = (float*)d_ws;                // [B][8][LQ][K] = 2.8 MB

    dim3 grid(NCH, B_);
    knrm_main<<<grid, 256, 0, stream>>>(Q, D, md, psum);
    knrm_final<<<B_, 64, 0, stream>>>(psum, mq, dw, db, out);
}

// Round 8
// 150.795 us; speedup vs baseline: 1.1944x; 1.0035x over previous
//
#include <hip/hip_runtime.h>
#include <hip/hip_bf16.h>
#include <math.h>

#define B_   128
#define LQ_  64
#define LD_  512
#define E_   300
#define K_   11
#define NCH  8      // d-chunks of 64 rows
#define DCH  64
#define NT   10     // e-tiles of 32 (300 padded to 320)
#define QSTR 328    // Q bf16 LDS row stride (2-way bank alias = free)
#define CSTR 68     // epilogue sims row stride (floats)

typedef __bf16  bf16x8  __attribute__((ext_vector_type(8)));
typedef float   floatx4 __attribute__((ext_vector_type(4)));

__device__ __constant__ float MU_C[K_] =
    {1.0f, 0.9f, 0.7f, 0.5f, 0.3f, 0.1f, -0.1f, -0.3f, -0.5f, -0.7f, -0.9f};
__device__ __constant__ float NEGC_C[K_] =
    {-500000.0f, -50.0f, -50.0f, -50.0f, -50.0f, -50.0f,
     -50.0f, -50.0f, -50.0f, -50.0f, -50.0f};

__device__ __forceinline__ unsigned int pk2(float x, float y) {
    __hip_bfloat162 h = __float22bfloat162_rn(make_float2(x, y));
    union { __hip_bfloat162 h2; unsigned int u; } c;
    c.h2 = h;
    return c.u;
}
__device__ __forceinline__ float bsq(unsigned int u) {
    float lo = __uint_as_float(u << 16);
    float hi = __uint_as_float(u & 0xffff0000u);
    return fmaf(lo, lo, hi * hi);
}
__device__ __forceinline__ float bperm(int idx4, float v) {
    return __int_as_float(__builtin_amdgcn_ds_bpermute(idx4, __float_as_int(v)));
}

union __align__(16) ShQ {
    unsigned short qs[LQ_ * QSTR];  // 41984 B: K-loop Q (bf16, zero-padded to 320)
    float          cs[LQ_ * CSTR];  // 17408 B: epilogue normalized sims
};

// Block = (batch, d-chunk of 64), 256 thr = 4 waves; wave w owns d-rows w*16..+16.
// D: ONE 20-deep burst of coalesced dwordx4 into registers (structurally
// un-collapsible pipeline; 128-B segments), fragment order recovered per tile
// with 8 ds_bpermute. K-loop has ZERO vmem. Q: staged once -> bf16 LDS.
__global__ __launch_bounds__(256, 3) void knrm_main(
    const float* __restrict__ Q, const float* __restrict__ D,
    const float* __restrict__ mask_d, float* __restrict__ psum)
{
    const int b = blockIdx.x, ch = blockIdx.y, d0 = ch * DCH;  // same-batch chunks share an XCD
    const int tid  = threadIdx.x;
    const int lane = tid & 63;
    const int w    = tid >> 6;
    const int quad = lane >> 4;
    const int l15  = lane & 15;
    const int jr   = lane >> 2;    // 0..15: this lane's d-row (coalesced domain)
    const int jc   = lane & 3;     // col-block (8 floats) within a 32-elem tile

    __shared__ ShQ sh;
    __shared__ float qinv_s[LQ_];
    __shared__ float dinv_s[DCH];
    __shared__ float md_s[DCH];

    // ---- D burst: 20 independent coalesced dwordx4 -> registers ----
    const float* drow = D + ((size_t)b * LD_ + d0 + w * 16 + jr) * E_;
    float4 dreg[2 * NT];
#pragma unroll
    for (int t = 0; t < NT; ++t) {
        const int c0 = t * 32 + jc * 8;
        if (t < NT - 1) {
            dreg[2 * t]     = *(const float4*)(drow + c0);
            dreg[2 * t + 1] = *(const float4*)(drow + c0 + 4);
        } else {  // tile 9: cols >= 300 clamped to row start, masked at use
            dreg[2 * t]     = *(const float4*)(drow + (jc <= 1 ? c0 : 0));
            dreg[2 * t + 1] = *(const float4*)(drow + (jc == 0 ? c0 + 4 : 0));
        }
    }
    __builtin_amdgcn_sched_barrier(0);   // pin: all 20 loads issue before anything else

    // ---- Q staging (fp32 -> bf16, zero-padded e>=300) ----
    const float* qbase = Q + (size_t)b * LQ_ * E_;
#pragma unroll
    for (int kk = 0; kk < 10; ++kk) {
        int g = tid + kk * 256;                    // 2560 units of 8 elems
        int row = (unsigned)g / 40u;
        int u   = g - row * 40;
        int e   = u * 8;
        const float* src = qbase + (size_t)row * E_;
        float4 v0 = (e     < E_) ? *(const float4*)(src + e)
                                 : make_float4(0.f, 0.f, 0.f, 0.f);
        float4 v1 = (e + 4 < E_) ? *(const float4*)(src + e + 4)
                                 : make_float4(0.f, 0.f, 0.f, 0.f);
        *(uint4*)&sh.qs[row * QSTR + e] =
            make_uint4(pk2(v0.x, v0.y), pk2(v0.z, v0.w),
                       pk2(v1.x, v1.y), pk2(v1.z, v1.w));
    }
    if (tid < DCH) md_s[tid] = mask_d[(size_t)b * LD_ + d0 + tid];

    // q norms from staged bf16 (4 thr/row)
    {
        int row = tid >> 2, part = tid & 3;
        float ss = 0.f;
#pragma unroll
        for (int j2 = 0; j2 < 10; ++j2) {
            uint4 uv = *(const uint4*)&sh.qs[row * QSTR + part * 80 + j2 * 8];
            ss += bsq(uv.x) + bsq(uv.y) + bsq(uv.z) + bsq(uv.w);
        }
        ss += __shfl_xor(ss, 1);
        ss += __shfl_xor(ss, 2);
        if (part == 0) qinv_s[row] = 1.0f / fmaxf(sqrtf(ss), 1e-12f);
    }
    __syncthreads();   // Qs + qinv + md ready

    // ---- K-loop: bpermute-redistribute D + MFMA; zero vmem ----
    const int src4 = ((l15 << 2) | quad) << 2;   // bpermute byte index
    const float m0 = (jc <= 1) ? 1.f : 0.f;      // tile-9 validity masks
    const float m1 = (jc == 0) ? 1.f : 0.f;

    floatx4 acc[4];
    floatx4 zero4 = {0.f, 0.f, 0.f, 0.f};
#pragma unroll
    for (int mt = 0; mt < 4; ++mt) acc[mt] = zero4;
    float ssd = 0.f;

#pragma unroll
    for (int t = 0; t < NT; ++t) {
        float4 a = dreg[2 * t], c = dreg[2 * t + 1];
        if (t == NT - 1) {
            a.x *= m0; a.y *= m0; a.z *= m0; a.w *= m0;
            c.x *= m1; c.y *= m1; c.z *= m1; c.w *= m1;
        }
        ssd += a.x * a.x + a.y * a.y + a.z * a.z + a.w * a.w;
        ssd += c.x * c.x + c.y * c.y + c.z * c.z + c.w * c.w;

        float bv[8];
        bv[0] = bperm(src4, a.x); bv[1] = bperm(src4, a.y);
        bv[2] = bperm(src4, a.z); bv[3] = bperm(src4, a.w);
        bv[4] = bperm(src4, c.x); bv[5] = bperm(src4, c.y);
        bv[6] = bperm(src4, c.z); bv[7] = bperm(src4, c.w);

        union { uint4 u; bf16x8 v; } bc;
        bc.u = make_uint4(pk2(bv[0], bv[1]), pk2(bv[2], bv[3]),
                          pk2(bv[4], bv[5]), pk2(bv[6], bv[7]));
        const int ebase = t * 32 + quad * 8;
#pragma unroll
        for (int mt = 0; mt < 4; ++mt) {
            bf16x8 af = *(const bf16x8*)&sh.qs[(mt * 16 + l15) * QSTR + ebase];
            acc[mt] = __builtin_amdgcn_mfma_f32_16x16x32_bf16(af, bc.v, acc[mt], 0, 0, 0);
        }
    }

    // d norms: lane's ssd covers row jr, its 80 cols; combine the 4 col-lanes
    ssd += __shfl_xor(ssd, 1);
    ssd += __shfl_xor(ssd, 2);
    if (jc == 0) dinv_s[w * 16 + jr] = 1.0f / fmaxf(sqrtf(ssd), 1e-12f);
    const float dinv = dinv_s[w * 16 + l15];   // same-wave write -> lgkm wait

    // ---- epilogue: normalized sims -> LDS (aliases Qs), repartition, pool ----
    __syncthreads();   // all Qs reads done before aliasing as cs
#pragma unroll
    for (int mt = 0; mt < 4; ++mt) {
#pragma unroll
        for (int r = 0; r < 4; ++r) {
            int q = mt * 16 + quad * 4 + r;
            sh.cs[q * CSTR + w * 16 + l15] = acc[mt][r] * qinv_s[q] * dinv;
        }
    }
    __syncthreads();

    const int pq = tid >> 2, pd = tid & 3;   // q-row x 16-d slice
    float kacc[K_];
#pragma unroll
    for (int k = 0; k < K_; ++k) kacc[k] = 0.f;
#pragma unroll
    for (int j = 0; j < 16; ++j) {
        float s = sh.cs[pq * CSTR + pd * 16 + j];
        float m = md_s[pd * 16 + j];
#pragma unroll
        for (int k = 0; k < K_; ++k) {
            float df = s - MU_C[k];
            kacc[k] = fmaf(__expf(df * df * NEGC_C[k]), m, kacc[k]);
        }
    }
#pragma unroll
    for (int msk = 1; msk <= 2; msk <<= 1)
#pragma unroll
        for (int k = 0; k < K_; ++k) kacc[k] += __shfl_xor(kacc[k], msk);

    if (pd == 0) {
        const size_t base = (((size_t)b * NCH + ch) * LQ_ + pq) * K_;
#pragma unroll
        for (int k = 0; k < K_; ++k) psum[base + k] = kacc[k];
    }
}

// Combine chunk partials, log-pool, dense + tanh. One wave per batch.
__global__ __launch_bounds__(64) void knrm_final(
    const float* __restrict__ psum, const float* __restrict__ mask_q,
    const float* __restrict__ dw, const float* __restrict__ db,
    float* __restrict__ out)
{
    const int b = blockIdx.x;
    const int q = threadIdx.x;  // 0..63

    float t = 0.0f;
#pragma unroll
    for (int k = 0; k < K_; ++k) {
        float p = 0.0f;
#pragma unroll
        for (int c = 0; c < NCH; ++c)
            p += psum[(((size_t)b * NCH + c) * LQ_ + q) * K_ + k];
        p = fmaxf(p, 1e-10f);
        t += logf(p) * dw[k];
    }
    t *= 0.01f * mask_q[(size_t)b * LQ_ + q];

#pragma unroll
    for (int m = 32; m >= 1; m >>= 1) t += __shfl_xor(t, m);
    if (q == 0) out[b] = tanhf(t + db[0]);
}

extern "C" void kernel_launch(void* const* d_in, const int* in_sizes, int n_in,
                              void* d_out, int out_size, void* d_ws, size_t ws_size,
                              hipStream_t stream) {
    const float* Q   = (const float*)d_in[0];  // [B, LQ, E]
    const float* D   = (const float*)d_in[1];  // [B, LD, E]
    const float* mq  = (const float*)d_in[2];  // [B, LQ]
    const float* md  = (const float*)d_in[3];  // [B, LD]
    const float* dw  = (const float*)d_in[4];  // [1, K]
    const float* db  = (const float*)d_in[5];  // [1]
    float* out  = (float*)d_out;               // [B, 1]
    float* psum = (float*)d_ws;                // [B][8][LQ][K] = 2.8 MB

    dim3 grid(B_, NCH);                        // same-batch chunks -> same XCD
    knrm_main<<<grid, 256, 0, stream>>>(Q, D, md, psum);
    knrm_final<<<B_, 64, 0, stream>>>(psum, mq, dw, db, out);
}

// Round 9
// 140.721 us; speedup vs baseline: 1.2799x; 1.0716x over previous
//
#include <hip/hip_runtime.h>
#include <hip/hip_bf16.h>
#include <math.h>

#define B_   128
#define LQ_  64
#define LD_  512
#define E_   300
#define K_   11
#define NCH  8      // d-chunks of 64 rows
#define DCH  64
#define NT   10     // e-tiles of 32 (300 padded to 320)
#define QSTR 328    // Q bf16 LDS row stride (2-way bank alias = free)
#define CSTR 68     // epilogue sims row stride (floats)

typedef __bf16  bf16x8  __attribute__((ext_vector_type(8)));
typedef float   floatx4 __attribute__((ext_vector_type(4)));

// factorized RBF: kernel k (1..10, mu=0.9..-0.9 step -0.2, sigma=0.1):
//   exp(-50(s-mu_k)^2) = t_k * CK2[k],  t_1 = exp(90s-50s^2), t_{k+1} = t_k*exp(-20s)
__device__ __constant__ float CK2_C[10] =
    {2.576757e-18f, 2.288464e-11f, 3.726653e-06f, 1.110900e-02f, 6.065307e-01f,
     6.065307e-01f, 1.110900e-02f, 3.726653e-06f, 2.288464e-11f, 2.576757e-18f};

__device__ __forceinline__ unsigned int pk2(float x, float y) {
    __hip_bfloat162 h = __float22bfloat162_rn(make_float2(x, y));
    union { __hip_bfloat162 h2; unsigned int u; } c;
    c.h2 = h;
    return c.u;
}

union __align__(16) ShQ {
    unsigned short qs[LQ_ * QSTR];  // 41984 B: K-loop Q (bf16, zero-padded to 320)
    float          cs[LQ_ * CSTR];  // 17408 B: epilogue normalized sims
};

// Block = (batch, d-chunk of 64), 256 thr = 4 waves; wave w owns d-rows w*16..+16.
// Q: staged once -> bf16 LDS (norms fused, fp32). D: B-fragments straight from
// global (L3/L2-hot via XCD swizzle: all chunks of batch b land on XCD b%8).
// Epilogue: factorized RBF (3 exps per sim element instead of 11).
__global__ __launch_bounds__(256, 3) void knrm_main(
    const float* __restrict__ Q, const float* __restrict__ D,
    const float* __restrict__ mask_d, float* __restrict__ psum)
{
    const int b = blockIdx.x, ch = blockIdx.y, d0 = ch * DCH;
    const int tid  = threadIdx.x;
    const int lane = tid & 63;
    const int w    = tid >> 6;
    const int quad = lane >> 4;
    const int l15  = lane & 15;

    __shared__ ShQ sh;
    __shared__ float qinv_s[LQ_];
    __shared__ float md_s[DCH];

    // ---- Q staging (fp32 -> bf16, zero-padded e>=300) with fused norms ----
    // 4 threads per q-row, 80 elems each (10 x 8).
    const int qrow = tid >> 2, qpart = tid & 3;
    const float* qp = Q + ((size_t)b * LQ_ + qrow) * E_;
    float ssq = 0.f;
#pragma unroll
    for (int j = 0; j < 10; ++j) {
        int e = qpart * 80 + j * 8;
        float4 v0 = (e     < E_) ? *(const float4*)(qp + e)
                                 : make_float4(0.f, 0.f, 0.f, 0.f);
        float4 v1 = (e + 4 < E_) ? *(const float4*)(qp + e + 4)
                                 : make_float4(0.f, 0.f, 0.f, 0.f);
        ssq += v0.x * v0.x + v0.y * v0.y + v0.z * v0.z + v0.w * v0.w;
        ssq += v1.x * v1.x + v1.y * v1.y + v1.z * v1.z + v1.w * v1.w;
        *(uint4*)&sh.qs[qrow * QSTR + e] =
            make_uint4(pk2(v0.x, v0.y), pk2(v0.z, v0.w),
                       pk2(v1.x, v1.y), pk2(v1.z, v1.w));
    }
    ssq += __shfl_xor(ssq, 1);
    ssq += __shfl_xor(ssq, 2);
    if (qpart == 0) qinv_s[qrow] = 1.0f / fmaxf(sqrtf(ssq), 1e-12f);
    if (tid < DCH) md_s[tid] = mask_d[(size_t)b * LD_ + d0 + tid];
    __syncthreads();   // Qs + qinv + md ready

    // ---- K-loop: D B-frags direct from global + MFMA ----
    // Lane (l15,quad): row d0+w*16+l15, cols t*32+quad*8..+8. Per row the 4
    // quads cover 128 contiguous bytes -> 64-B coalesced segments.
    const float* drow = D + ((size_t)b * LD_ + d0 + w * 16 + l15) * E_;
    const float tm0 = (quad <= 1) ? 1.f : 0.f;            // tile-9 validity
    const float tm1 = (quad == 0) ? 1.f : 0.f;            // (cols >= 300 masked)

    floatx4 acc[4];
    floatx4 zero4 = {0.f, 0.f, 0.f, 0.f};
#pragma unroll
    for (int mt = 0; mt < 4; ++mt) acc[mt] = zero4;
    float ssd = 0.f;

#pragma unroll
    for (int t = 0; t < NT; ++t) {
        const int c0 = t * 32 + quad * 8;
        float4 a, c;
        if (t < NT - 1) {
            a = *(const float4*)(drow + c0);
            c = *(const float4*)(drow + c0 + 4);
        } else {   // tile 9: quad0 fully valid, quad1 half, quads 2-3 invalid
            a = *(const float4*)(drow + (quad <= 1 ? c0 : 0));
            c = *(const float4*)(drow + (quad == 0 ? c0 + 4 : 0));
            a.x *= tm0; a.y *= tm0; a.z *= tm0; a.w *= tm0;
            c.x *= tm1; c.y *= tm1; c.z *= tm1; c.w *= tm1;
        }
        ssd += a.x * a.x + a.y * a.y + a.z * a.z + a.w * a.w;
        ssd += c.x * c.x + c.y * c.y + c.z * c.z + c.w * c.w;

        union { uint4 u; bf16x8 v; } bc;
        bc.u = make_uint4(pk2(a.x, a.y), pk2(a.z, a.w),
                          pk2(c.x, c.y), pk2(c.z, c.w));
        const int ebase = t * 32 + quad * 8;
#pragma unroll
        for (int mt = 0; mt < 4; ++mt) {
            bf16x8 af = *(const bf16x8*)&sh.qs[(mt * 16 + l15) * QSTR + ebase];
            acc[mt] = __builtin_amdgcn_mfma_f32_16x16x32_bf16(af, bc.v, acc[mt], 0, 0, 0);
        }
    }

    // d inv-norm: the 4 quads of same l15 covered disjoint col ranges
    ssd += __shfl_xor(ssd, 16);
    ssd += __shfl_xor(ssd, 32);
    const float dinv = 1.0f / fmaxf(sqrtf(ssd), 1e-12f);

    // ---- epilogue: normalized sims -> LDS (aliases Qs), repartition, pool ----
    __syncthreads();   // all Qs fragment reads done before aliasing as cs
#pragma unroll
    for (int mt = 0; mt < 4; ++mt) {
#pragma unroll
        for (int r = 0; r < 4; ++r) {
            int q = mt * 16 + quad * 4 + r;
            sh.cs[q * CSTR + w * 16 + l15] = acc[mt][r] * qinv_s[q] * dinv;
        }
    }
    __syncthreads();

    const int pq = tid >> 2, pd = tid & 3;   // q-row x 16-d slice
    float kacc[K_];
#pragma unroll
    for (int k = 0; k < K_; ++k) kacc[k] = 0.f;
#pragma unroll
    for (int j = 0; j < 16; ++j) {
        float s = sh.cs[pq * CSTR + pd * 16 + j];
        float m = md_s[pd * 16 + j];
        // kernel 0 (sigma=0.001): exact
        float df0 = s - 1.0f;
        kacc[0] = fmaf(__expf(df0 * df0 * -500000.0f), m, kacc[0]);
        // kernels 1..10: factorized (3 exps total)
        float t1 = __expf(fmaf(-50.0f * s, s, 90.0f * s));  // arg <= 40.5, no ovf
        float r  = __expf(-20.0f * s);
        float t  = t1 * m;
#pragma unroll
        for (int k = 1; k < K_; ++k) {
            kacc[k] = fmaf(t, CK2_C[k - 1], kacc[k]);
            t *= r;
        }
    }
#pragma unroll
    for (int msk = 1; msk <= 2; msk <<= 1)
#pragma unroll
        for (int k = 0; k < K_; ++k) kacc[k] += __shfl_xor(kacc[k], msk);

    if (pd == 0) {
        const size_t base = (((size_t)b * NCH + ch) * LQ_ + pq) * K_;
#pragma unroll
        for (int k = 0; k < K_; ++k) psum[base + k] = kacc[k];
    }
}

// Combine chunk partials, log-pool, dense + tanh. One wave per batch.
__global__ __launch_bounds__(64) void knrm_final(
    const float* __restrict__ psum, const float* __restrict__ mask_q,
    const float* __restrict__ dw, const float* __restrict__ db,
    float* __restrict__ out)
{
    const int b = blockIdx.x;
    const int q = threadIdx.x;  // 0..63

    float t = 0.0f;
#pragma unroll
    for (int k = 0; k < K_; ++k) {
        float p = 0.0f;
#pragma unroll
        for (int c = 0; c < NCH; ++c)
            p += psum[(((size_t)b * NCH + c) * LQ_ + q) * K_ + k];
        p = fmaxf(p, 1e-10f);
        t += logf(p) * dw[k];
    }
    t *= 0.01f * mask_q[(size_t)b * LQ_ + q];

#pragma unroll
    for (int m = 32; m >= 1; m >>= 1) t += __shfl_xor(t, m);
    if (q == 0) out[b] = tanhf(t + db[0]);
}

extern "C" void kernel_launch(void* const* d_in, const int* in_sizes, int n_in,
                              void* d_out, int out_size, void* d_ws, size_t ws_size,
                              hipStream_t stream) {
    const float* Q   = (const float*)d_in[0];  // [B, LQ, E]
    const float* D   = (const float*)d_in[1];  // [B, LD, E]
    const float* mq  = (const float*)d_in[2];  // [B, LQ]
    const float* md  = (const float*)d_in[3];  // [B, LD]
    const float* dw  = (const float*)d_in[4];  // [1, K]
    const float* db  = (const float*)d_in[5];  // [1]
    float* out  = (float*)d_out;               // [B, 1]
    float* psum = (float*)d_ws;                // [B][8][LQ][K] = 2.8 MB

    dim3 grid(B_, NCH);                        // same-batch chunks -> same XCD
    knrm_main<<<grid, 256, 0, stream>>>(Q, D, md, psum);
    knrm_final<<<B_, 64, 0, stream>>>(psum, mq, dw, db, out);
}